// Round 3
// baseline (386.414 us; speedup 1.0000x reference)
//
#include <hip/hip_runtime.h>
#include <hip/hip_bf16.h>
#include <cstdint>

// ---------------------------------------------------------------------------
// Attention (B=4, L=2048, C=1024, H=16, D=64). f32 in / f32 out, bf16 MFMA.
//   convert_all -> gemm_qkv(+v-transpose fused) -> rope_qk(q pre-scaled by
//   0.125*log2e) -> flash_attn -> gemm_proj
// flash_attn v7: att[2] cross-tile pipeline. PV(t-1) executes during iter t
// from register-held P/V fragments, overlapping tile t's exp2/pack (trans
// pipe) with PV(t-1) (matrix pipe) -- the v5/v6 rounds proved the limiter is
// the serial QK->exp2->pack->swap->PV phase chain (occupancy 17->31% and
// bank-conflict 6.3M->0 both left dur unchanged at ~93us). s_setprio(1)
// wraps MFMA clusters (waves now sit at different phases -> arbitration
// helps, m191). V frags for tile t are read at END of iter t: LDS latency
// hides under barrier+QK(t+1); lifetime safe (lgkm drained at own barrier
// before any wave issues loads(t+2) into buf(t)).
// P never touches LDS: permuted K rows (bit2<->bit3 of n16) + permlane32_swap
// give the PV A-fragment in-register. Double-buffered K/V, ONE barrier per
// k-tile, exp2 softmax (q pre-scaled by 0.125*log2e in rope).
// MFMA 16x16x32 bf16 layouts (HW-verified): A/B: [lane&15][(lane>>4)*8+j];
// C/D: col=lane&15, row=(lane>>4)*4+reg.
// permlane32_swap(a,b): r.x = [a_lo | b_lo], r.y = [a_hi | b_hi].
// ---------------------------------------------------------------------------

typedef unsigned short u16;
typedef __attribute__((ext_vector_type(8))) short bf16x8;
typedef __attribute__((ext_vector_type(4))) float f32x4;
typedef __attribute__((ext_vector_type(2))) unsigned int u32x2;

#define GLD16(g, l)                                                            \
  __builtin_amdgcn_global_load_lds(                                            \
      (const __attribute__((address_space(1))) void*)(g),                      \
      (__attribute__((address_space(3))) void*)(l), 16, 0, 0)

static __device__ __forceinline__ u16 f32_bf16(float f) {
  union { float f; unsigned u; } v; v.f = f;
  unsigned r = v.u + 0x7FFFu + ((v.u >> 16) & 1u);  // RNE
  return (u16)(r >> 16);
}
static __device__ __forceinline__ float bf16_f32(u16 h) {
  union { unsigned u; float f; } v; v.u = ((unsigned)h) << 16;
  return v.f;
}
static __device__ __forceinline__ unsigned pack_rne(float a, float b) {
  union { float f; unsigned u; } x, y; x.f = a; y.f = b;
  unsigned ua = x.u + 0x7FFFu + ((x.u >> 16) & 1u);
  unsigned ub = y.u + 0x7FFFu + ((y.u >> 16) & 1u);
  return (ua >> 16) | (ub & 0xFFFF0000u);
}
static __device__ __forceinline__ unsigned pack_bf16_hw(float a, float b) {
  float2 t; t.x = a; t.y = b;
  __hip_bfloat162 h = __float22bfloat162_rn(t);
  union { __hip_bfloat162 h; unsigned u; } c; c.h = h;
  return c.u;
}
static __device__ __forceinline__ bf16x8 mk_pf(unsigned a, unsigned b,
                                               unsigned c, unsigned d) {
  union { unsigned u[4]; bf16x8 v; } t;
  t.u[0] = a; t.u[1] = b; t.u[2] = c; t.u[3] = d;
  return t.v;
}

// ---------------------------------------------------------------------------
// K0: canonicalize ALL inputs to bf16 in one launch; dtype flag read inline
// (cos[0][0]==1.0f: f32 word 0x3F800000, bf16 pair 0x3F803F80).
__global__ __launch_bounds__(256) void convert_all(
    const void* __restrict__ x, const void* __restrict__ wq,
    const void* __restrict__ wp, const void* __restrict__ cs,
    const void* __restrict__ sn, const void* __restrict__ bs,
    u16* __restrict__ xb, u16* __restrict__ wqb, u16* __restrict__ wpb,
    u16* __restrict__ cb, u16* __restrict__ sb, u16* __restrict__ bb) {
  const unsigned f32mode = (((const unsigned*)cs)[0] == 0x3F800000u);
  int blk = blockIdx.x;
  const void* src; u16* dst; int i0, n4;
  if (blk < 8192)       { src = x;  dst = xb;  i0 = blk;         n4 = 2097152; }
  else if (blk < 11264) { src = wq; dst = wqb; i0 = blk - 8192;  n4 = 786432; }
  else if (blk < 12288) { src = wp; dst = wpb; i0 = blk - 11264; n4 = 262144; }
  else if (blk < 12352) { src = cs; dst = cb;  i0 = blk - 12288; n4 = 16384; }
  else if (blk < 12416) { src = sn; dst = sb;  i0 = blk - 12352; n4 = 16384; }
  else                  { src = bs; dst = bb;  i0 = blk - 12416; n4 = 256; }
  int i = i0 * 256 + threadIdx.x;
  if (i >= n4) return;
  if (f32mode) {
    float4 v = ((const float4*)src)[i];
    uint2 o;
    o.x = pack_rne(v.x, v.y);
    o.y = pack_rne(v.z, v.w);
    ((uint2*)dst)[i] = o;
  } else {
    ((uint2*)dst)[i] = ((const uint2*)src)[i];
  }
}

// ---------------------------------------------------------------------------
// Shared GEMM mainloop: C[128x128] = A[MxK] * B[NxK]^T, BK=32, 4 waves 2x2.
static __device__ __forceinline__ void gemm_mainloop(
    const u16* __restrict__ A, const u16* __restrict__ Bm, int K,
    int m0, int n0, u16* As, u16* Bs, f32x4 acc[4][4]) {
  const int tid  = threadIdx.x;
  const int lane = tid & 63;
  const int wave = tid >> 6;
  const int n16  = lane & 15;
  const int quad = lane >> 4;
  const int wm = (wave >> 1) * 64;
  const int wn = (wave & 1) * 64;
  const u16* ag = A  + (size_t)(m0 + wave * 16 + (lane >> 2)) * K + (lane & 3) * 8;
  const u16* bg = Bm + (size_t)(n0 + wave * 16 + (lane >> 2)) * K + (lane & 3) * 8;
  u16* al = As + wave * (16 * 32);
  u16* bl = Bs + wave * (16 * 32);
  for (int kt = 0; kt < K; kt += 32) {
    GLD16(ag + kt, al);
    GLD16(ag + (size_t)64 * K + kt, al + 64 * 32);
    GLD16(bg + kt, bl);
    GLD16(bg + (size_t)64 * K + kt, bl + 64 * 32);
    __syncthreads();
    bf16x8 af[4], bf[4];
#pragma unroll
    for (int i = 0; i < 4; i++)
      af[i] = *(const bf16x8*)(As + (wm + i * 16 + n16) * 32 + quad * 8);
#pragma unroll
    for (int j = 0; j < 4; j++)
      bf[j] = *(const bf16x8*)(Bs + (wn + j * 16 + n16) * 32 + quad * 8);
#pragma unroll
    for (int i = 0; i < 4; i++)
#pragma unroll
      for (int j = 0; j < 4; j++)
        acc[i][j] = __builtin_amdgcn_mfma_f32_16x16x32_bf16(af[i], bf[j], acc[i][j], 0, 0, 0);
    __syncthreads();
  }
}

// ---------------------------------------------------------------------------
// K1: qkv = x @ w_qkv^T; q,k -> [B][H][L][D]; v -> [B][H][D][L] (transposed
// in-epilogue: for fixed (i,j), r=0..3 are 4 consecutive l at one d -> b64).
__global__ __launch_bounds__(256) void gemm_qkv(
    const u16* __restrict__ x, const u16* __restrict__ w,
    u16* __restrict__ q_ws, u16* __restrict__ k_ws, u16* __restrict__ vt_ws) {
  __shared__ u16 As[128 * 32];
  __shared__ u16 Bs[128 * 32];
  f32x4 acc[4][4];
#pragma unroll
  for (int i = 0; i < 4; i++)
#pragma unroll
    for (int j = 0; j < 4; j++) acc[i][j] = (f32x4){0.f, 0.f, 0.f, 0.f};
  const int m0 = blockIdx.y * 128;
  const int n0 = blockIdx.x * 128;
  gemm_mainloop(x, w, 1024, m0, n0, As, Bs, acc);
  const int lane = threadIdx.x & 63, wave = threadIdx.x >> 6;
  const int n16 = lane & 15, quad = lane >> 4;
  const int wm = (wave >> 1) * 64, wn = (wave & 1) * 64;
#pragma unroll
  for (int i = 0; i < 4; i++)
#pragma unroll
    for (int j = 0; j < 4; j++) {
      int f = n0 + wn + j * 16 + n16;            // 0..3071
      int which = f >> 10;
      int rem = f & 1023;
      int h = rem >> 6, d = rem & 63;
      int l0 = m0 + wm + i * 16 + quad * 4;      // 4 consecutive rows
      int b = l0 >> 11, l = l0 & 2047;
      if (which == 2) {
        uint2 o;
        o.x = pack_rne(acc[i][j][0], acc[i][j][1]);
        o.y = pack_rne(acc[i][j][2], acc[i][j][3]);
        size_t idx = (((size_t)b * 16 + h) * 64 + d) * 2048 + l;
        *(uint2*)(vt_ws + idx) = o;
      } else {
        u16* dst = (which == 0) ? q_ws : k_ws;
        size_t base = (((size_t)b * 16 + h) * 2048 + l) * 64 + d;
#pragma unroll
        for (int r = 0; r < 4; r++)
          dst[base + (size_t)r * 64] = f32_bf16(acc[i][j][r]);
      }
    }
}

// ---------------------------------------------------------------------------
// K2: RoPE in-place on q and k. q additionally pre-scaled by 0.125*log2(e)
// so flash_attn's softmax is p = exp2(q'.k) with zero extra muls.
#define NP_ROPE 4194304  // B*H*L*(D/2)
__global__ __launch_bounds__(256) void rope_qk(
    u16* __restrict__ q, u16* __restrict__ k,
    const u16* __restrict__ cosp, const u16* __restrict__ sinp) {
  int idx = blockIdx.x * 256 + threadIdx.x;
  bool isq = (idx < NP_ROPE);
  u16* t = isq ? q : k;
  float sc = isq ? 0.18033688011112042f : 1.0f;  // 0.125 * log2(e)
  int p = isq ? idx : idx - NP_ROPE;
  int l = (p >> 5) & 2047;
  int i = p & 31;
  unsigned v = ((unsigned*)t)[p];
  float te = bf16_f32((u16)(v & 0xFFFFu));
  float to = bf16_f32((u16)(v >> 16));
  float c = bf16_f32(cosp[l * 32 + i]);
  float s = bf16_f32(sinp[l * 32 + i]);
  ((unsigned*)t)[p] = pack_rne((te * c - to * s) * sc, (te * s + to * c) * sc);
}

// ---------------------------------------------------------------------------
// K4: flash attention v7. 1-D grid 1024, bh-major (bh=id&63 -> XCD=bh%8;
// same-bh blocks are == mod 64 -> same XCD -> K/V L2 reuse).
// Block = 128 queries, 4 waves x 32 q (2 q-blocks of 16). att[2] pipeline:
// PV(t-1) from registers during iter t; V frags read at end of iter t.
__global__ __launch_bounds__(256, 4) void flash_attn(
    const u16* __restrict__ q_ws, const u16* __restrict__ k_ws,
    const u16* __restrict__ vt_ws, u16* __restrict__ o_ws) {
  __shared__ u16 Ks[2][64 * 64];   // [key][d], 16B chunks XOR-swizzled
  __shared__ u16 Vs[2][64 * 64];   // [d][key], 16B chunks XOR-swizzled
  const int bh = blockIdx.x & 63;
  const int q0 = (blockIdx.x >> 6) * 128;
  const int b = bh >> 4, h = bh & 15;
  const int tid = threadIdx.x, lane = tid & 63, wave = tid >> 6;
  const int n16 = lane & 15, quad = lane >> 4;
  const int x7 = n16 & 7;
  // permuted K-row index: swap bits 2<->3 of n16. QK^T output rows then come
  // out key-permuted such that one lane<->lane+32 half-swap of the packed
  // bf16 pairs yields the PV A-fragment (keys quad*8+j) directly.
  const int pn16 = (n16 & 3) | ((n16 & 4) << 1) | ((n16 & 8) >> 1);
  const int px7 = pn16 & 7;
  const size_t hoff = (size_t)bh * (2048 * 64);

  // Q fragments, 2 q-blocks (B-operand: n=q=lane&15, k=d=quad*8+j)
  bf16x8 qf[2][2];
#pragma unroll
  for (int qb = 0; qb < 2; qb++) {
    const u16* qrow = q_ws + hoff + (size_t)(q0 + wave * 32 + qb * 16 + n16) * 64;
    qf[qb][0] = *(const bf16x8*)(qrow + quad * 8);
    qf[qb][1] = *(const bf16x8*)(qrow + 32 + quad * 8);
  }

  f32x4 oacc[2][4];
  f32x4 lq[2];
#pragma unroll
  for (int qb = 0; qb < 2; qb++) {
    lq[qb] = (f32x4){0.f, 0.f, 0.f, 0.f};
#pragma unroll
    for (int s = 0; s < 4; s++) oacc[qb][s] = (f32x4){0.f, 0.f, 0.f, 0.f};
  }

  // staging: lane covers row wave*8+(lane>>3), swizzled chunk (lane&7)^(row&7)
  const int srow = wave * 8 + (lane >> 3);
  const int sw = (lane & 7) ^ ((lane >> 3) & 7);
  const u16* kg = k_ws + hoff + (size_t)srow * 64 + sw * 8;
  const u16* vg = vt_ws + hoff + (size_t)srow * 2048 + sw * 8;
  const int loff = wave * 8 * 64;

  // preload tile 0 into buffer 0
  GLD16(kg, &Ks[0][loff]);
  GLD16(kg + 32 * 64, &Ks[0][loff + 32 * 64]);
  GLD16(vg, &Vs[0][loff]);
  GLD16(vg + (size_t)32 * 2048, &Vs[0][loff + 32 * 64]);

  // att[2] pipeline state: previous tile's P A-frags and V B-frags (regs).
  bf16x8 pfp[2][2];   // [qb][half]
  bf16x8 vfp[4][2];   // [sd][half]

  for (int kt = 0; kt < 2048; kt += 64) {
    const int buf = (kt >> 6) & 1;
    __syncthreads();  // drains tile-kt loads (issued a full compute phase ago)
    if (kt + 64 < 2048) {
      const u16* kgn = kg + (size_t)(kt + 64) * 64;
      const u16* vgn = vg + (kt + 64);
      GLD16(kgn, &Ks[buf ^ 1][loff]);
      GLD16(kgn + 32 * 64, &Ks[buf ^ 1][loff + 32 * 64]);
      GLD16(vgn, &Vs[buf ^ 1][loff]);
      GLD16(vgn + (size_t)32 * 2048, &Vs[buf ^ 1][loff + 32 * 64]);
    }
    const u16* ks = Ks[buf];
    const u16* vs = Vs[buf];

    // S^T per key-16-block (permuted K rows); K frags shared across 2 q-blocks.
    // Lane(n16,quad) after sub s holds actual keys s*16 + {r, r+8, r+4, r+12}
    // for quad = {0,1,2,3}, q = n16; packed to bf16 pairs px (p0,p1), py (p2,p3).
    unsigned pxk[2][4], pyk[2][4];  // [qb][sub]
#pragma unroll
    for (int sub = 0; sub < 4; sub++) {
      const u16* krow = ks + (sub * 16 + pn16) * 64;
      bf16x8 kf0 = *(const bf16x8*)(krow + (quad ^ px7) * 8);
      bf16x8 kf1 = *(const bf16x8*)(krow + ((quad + 4) ^ px7) * 8);
#pragma unroll
      for (int qb = 0; qb < 2; qb++) {
        f32x4 z = (f32x4){0.f, 0.f, 0.f, 0.f};
        __builtin_amdgcn_s_setprio(1);
        z = __builtin_amdgcn_mfma_f32_16x16x32_bf16(kf0, qf[qb][0], z, 0, 0, 0);
        z = __builtin_amdgcn_mfma_f32_16x16x32_bf16(kf1, qf[qb][1], z, 0, 0, 0);
        __builtin_amdgcn_s_setprio(0);
        f32x4 p;
#pragma unroll
        for (int r = 0; r < 4; r++) p[r] = __builtin_amdgcn_exp2f(z[r]);  // q pre-scaled
        lq[qb] += p;
        pxk[qb][sub] = pack_bf16_hw(p[0], p[1]);
        pyk[qb][sub] = pack_bf16_hw(p[2], p[3]);
      }
    }

    // PV(t-1): register-only MFMA cluster, independent of everything above ->
    // overlaps tile t's exp2/pack on the trans/VALU pipes.
    if (kt) {
      __builtin_amdgcn_s_setprio(1);
#pragma unroll
      for (int sd = 0; sd < 4; sd++)
#pragma unroll
        for (int qb = 0; qb < 2; qb++) {
          oacc[qb][sd] = __builtin_amdgcn_mfma_f32_16x16x32_bf16(pfp[qb][0], vfp[sd][0], oacc[qb][sd], 0, 0, 0);
          oacc[qb][sd] = __builtin_amdgcn_mfma_f32_16x16x32_bf16(pfp[qb][1], vfp[sd][1], oacc[qb][sd], 0, 0, 0);
        }
      __builtin_amdgcn_s_setprio(0);
    }

    // In-register transpose: permlane32_swap(a,b) -> r.x=[a_lo|b_lo],
    // r.y=[a_hi|b_hi]. With the pn16 row permutation this yields exactly the
    // PV A-operand: lane(n16,quad) reg m = keys {quad*8+2m, quad*8+2m+1}.
#pragma unroll
    for (int qb = 0; qb < 2; qb++) {
      u32x2 r0 = __builtin_amdgcn_permlane32_swap(pxk[qb][0], pxk[qb][1], false, false);
      u32x2 r1 = __builtin_amdgcn_permlane32_swap(pyk[qb][0], pyk[qb][1], false, false);
      u32x2 r2 = __builtin_amdgcn_permlane32_swap(pxk[qb][2], pxk[qb][3], false, false);
      u32x2 r3 = __builtin_amdgcn_permlane32_swap(pyk[qb][2], pyk[qb][3], false, false);
      pfp[qb][0] = mk_pf(r0.x, r1.x, r0.y, r1.y);
      pfp[qb][1] = mk_pf(r2.x, r3.x, r2.y, r3.y);
    }

    // Read V frags for tile t (consumed next iteration): issued last so the
    // LDS latency hides under barrier + QK(t+1). Safe vs loads(t+2): own
    // lgkm drains at the next barrier before any wave stages into buf(t).
#pragma unroll
    for (int sd = 0; sd < 4; sd++) {
      const u16* vrow = vs + (sd * 16 + n16) * 64;
      vfp[sd][0] = *(const bf16x8*)(vrow + (quad ^ x7) * 8);
      vfp[sd][1] = *(const bf16x8*)(vrow + ((quad + 4) ^ x7) * 8);
    }
  }

  // drain: PV for the final tile.
  __builtin_amdgcn_s_setprio(1);
#pragma unroll
  for (int sd = 0; sd < 4; sd++)
#pragma unroll
    for (int qb = 0; qb < 2; qb++) {
      oacc[qb][sd] = __builtin_amdgcn_mfma_f32_16x16x32_bf16(pfp[qb][0], vfp[sd][0], oacc[qb][sd], 0, 0, 0);
      oacc[qb][sd] = __builtin_amdgcn_mfma_f32_16x16x32_bf16(pfp[qb][1], vfp[sd][1], oacc[qb][sd], 0, 0, 0);
    }
  __builtin_amdgcn_s_setprio(0);

  // epilogue: per q-block, reduce l over quads, normalize, store bf16 o.
#pragma unroll
  for (int qb = 0; qb < 2; qb++) {
    float l = lq[qb][0] + lq[qb][1] + lq[qb][2] + lq[qb][3];
    l += __shfl_xor(l, 16, 64);
    l += __shfl_xor(l, 32, 64);
    float linv = 1.0f / l;
#pragma unroll
    for (int r = 0; r < 4; r++) {
      float lr = __shfl(linv, quad * 4 + r, 64);
      int row = q0 + wave * 32 + qb * 16 + quad * 4 + r;
      size_t base = ((size_t)b * 2048 + row) * 1024 + h * 64;
#pragma unroll
      for (int sd = 0; sd < 4; sd++)
        o_ws[base + sd * 16 + n16] = f32_bf16(oacc[qb][sd][r] * lr);
    }
  }
}

// ---------------------------------------------------------------------------
// K5: out = o @ w_proj^T + b_proj  -- f32 OUTPUT
__global__ __launch_bounds__(256) void gemm_proj(
    const u16* __restrict__ o, const u16* __restrict__ w,
    const u16* __restrict__ bias, float* __restrict__ out) {
  __shared__ u16 As[128 * 32];
  __shared__ u16 Bs[128 * 32];
  f32x4 acc[4][4];
#pragma unroll
  for (int i = 0; i < 4; i++)
#pragma unroll
    for (int j = 0; j < 4; j++) acc[i][j] = (f32x4){0.f, 0.f, 0.f, 0.f};
  const int m0 = blockIdx.y * 128;
  const int n0 = blockIdx.x * 128;
  gemm_mainloop(o, w, 1024, m0, n0, As, Bs, acc);
  const int lane = threadIdx.x & 63, wave = threadIdx.x >> 6;
  const int n16 = lane & 15, quad = lane >> 4;
  const int wm = (wave >> 1) * 64, wn = (wave & 1) * 64;
#pragma unroll
  for (int i = 0; i < 4; i++)
#pragma unroll
    for (int j = 0; j < 4; j++) {
      int f = n0 + wn + j * 16 + n16;
      float bf = bf16_f32(bias[f]);
#pragma unroll
      for (int r = 0; r < 4; r++) {
        int m = m0 + wm + i * 16 + quad * 4 + r;
        out[(size_t)m * 1024 + f] = acc[i][j][r] + bf;
      }
    }
}

// ---------------------------------------------------------------------------
extern "C" void kernel_launch(void* const* d_in, const int* in_sizes, int n_in,
                              void* d_out, int out_size, void* d_ws, size_t ws_size,
                              hipStream_t stream) {
  float* out = (float*)d_out;

  u16* ws = (u16*)d_ws;
  u16* xb     = ws;                   // 8388608  (dead after gemm_qkv)
  u16* wqkvb  = ws + 8388608;         // 3145728
  u16* wprojb = ws + 11534336;        // 1048576
  u16* cosb   = ws + 12582912;        // 65536
  u16* sinb   = ws + 12648448;        // 65536
  u16* biasb  = ws + 12713984;        // 1024
  u16* qb     = ws + 12715008;        // 8388608  [B][H][L][D]
  u16* kb     = ws + 21103616;        // 8388608  [B][H][L][D]
  u16* vtb    = ws + 29492224;        // 8388608  [B][H][D][L]
  u16* ob     = xb;                   // [B][L][C] overlay (xb dead)

  convert_all<<<12417, 256, 0, stream>>>(
      d_in[0], d_in[3], d_in[4], d_in[1], d_in[2], d_in[5],
      xb, wqkvb, wprojb, cosb, sinb, biasb);

  gemm_qkv<<<dim3(24, 64), 256, 0, stream>>>(xb, wqkvb, qb, kb, vtb);
  rope_qk<<<32768, 256, 0, stream>>>(qb, kb, cosb, sinb);
  flash_attn<<<1024, 256, 0, stream>>>(qb, kb, vtb, ob);
  gemm_proj<<<dim3(8, 64), 256, 0, stream>>>(ob, wprojb, biasb, out);
}

// Round 4
// 299.498 us; speedup vs baseline: 1.2902x; 1.2902x over previous
//
#include <hip/hip_runtime.h>
#include <hip/hip_bf16.h>
#include <cstdint>

// ---------------------------------------------------------------------------
// Attention (B=4, L=2048, C=1024, H=16, D=64). f32 in / f32 out, bf16 MFMA.
//   convert_all -> gemm_qkv(+v-transpose fused) -> rope_qk(q pre-scaled by
//   0.125*log2e) -> flash_attn -> gemm_proj
// flash_attn v8 = v7 att[2] pipeline with the spill fixed: launch_bounds
// (256,2) not (256,4). v7's (256,4) capped VGPR at 128 -> compiler spilled
// the cross-tile P/V register state to scratch (WRITE_SIZE 16MB -> 297MB,
// dur 93 -> 188us). R2 proved occupancy is NOT the limiter (17->31% = flat),
// so trading occupancy headroom for spill-free att[2] is the right call.
// att[2]: PV(t-1) executes during iter t from register-held P/V fragments,
// overlapping tile t's exp2/pack (trans pipe) with PV(t-1) (matrix pipe).
// s_setprio(1) wraps MFMA clusters. V frags for tile t read at END of iter
// t (LDS latency hides under barrier+QK(t+1); lifetime safe: own lgkm
// drains at next barrier before any wave stages into buf(t)).
// P never touches LDS: permuted K rows (bit2<->bit3 of n16) + permlane32_swap
// give the PV A-fragment in-register. Double-buffered K/V, ONE barrier per
// k-tile, exp2 softmax (q pre-scaled by 0.125*log2e in rope).
// MFMA 16x16x32 bf16 layouts (HW-verified): A/B: [lane&15][(lane>>4)*8+j];
// C/D: col=lane&15, row=(lane>>4)*4+reg.
// permlane32_swap(a,b): r.x = [a_lo | b_lo], r.y = [a_hi | b_hi].
// ---------------------------------------------------------------------------

typedef unsigned short u16;
typedef __attribute__((ext_vector_type(8))) short bf16x8;
typedef __attribute__((ext_vector_type(4))) float f32x4;
typedef __attribute__((ext_vector_type(2))) unsigned int u32x2;

#define GLD16(g, l)                                                            \
  __builtin_amdgcn_global_load_lds(                                            \
      (const __attribute__((address_space(1))) void*)(g),                      \
      (__attribute__((address_space(3))) void*)(l), 16, 0, 0)

static __device__ __forceinline__ u16 f32_bf16(float f) {
  union { float f; unsigned u; } v; v.f = f;
  unsigned r = v.u + 0x7FFFu + ((v.u >> 16) & 1u);  // RNE
  return (u16)(r >> 16);
}
static __device__ __forceinline__ float bf16_f32(u16 h) {
  union { unsigned u; float f; } v; v.u = ((unsigned)h) << 16;
  return v.f;
}
static __device__ __forceinline__ unsigned pack_rne(float a, float b) {
  union { float f; unsigned u; } x, y; x.f = a; y.f = b;
  unsigned ua = x.u + 0x7FFFu + ((x.u >> 16) & 1u);
  unsigned ub = y.u + 0x7FFFu + ((y.u >> 16) & 1u);
  return (ua >> 16) | (ub & 0xFFFF0000u);
}
static __device__ __forceinline__ unsigned pack_bf16_hw(float a, float b) {
  float2 t; t.x = a; t.y = b;
  __hip_bfloat162 h = __float22bfloat162_rn(t);
  union { __hip_bfloat162 h; unsigned u; } c; c.h = h;
  return c.u;
}
static __device__ __forceinline__ bf16x8 mk_pf(unsigned a, unsigned b,
                                               unsigned c, unsigned d) {
  union { unsigned u[4]; bf16x8 v; } t;
  t.u[0] = a; t.u[1] = b; t.u[2] = c; t.u[3] = d;
  return t.v;
}

// ---------------------------------------------------------------------------
// K0: canonicalize ALL inputs to bf16 in one launch; dtype flag read inline
// (cos[0][0]==1.0f: f32 word 0x3F800000, bf16 pair 0x3F803F80).
__global__ __launch_bounds__(256) void convert_all(
    const void* __restrict__ x, const void* __restrict__ wq,
    const void* __restrict__ wp, const void* __restrict__ cs,
    const void* __restrict__ sn, const void* __restrict__ bs,
    u16* __restrict__ xb, u16* __restrict__ wqb, u16* __restrict__ wpb,
    u16* __restrict__ cb, u16* __restrict__ sb, u16* __restrict__ bb) {
  const unsigned f32mode = (((const unsigned*)cs)[0] == 0x3F800000u);
  int blk = blockIdx.x;
  const void* src; u16* dst; int i0, n4;
  if (blk < 8192)       { src = x;  dst = xb;  i0 = blk;         n4 = 2097152; }
  else if (blk < 11264) { src = wq; dst = wqb; i0 = blk - 8192;  n4 = 786432; }
  else if (blk < 12288) { src = wp; dst = wpb; i0 = blk - 11264; n4 = 262144; }
  else if (blk < 12352) { src = cs; dst = cb;  i0 = blk - 12288; n4 = 16384; }
  else if (blk < 12416) { src = sn; dst = sb;  i0 = blk - 12352; n4 = 16384; }
  else                  { src = bs; dst = bb;  i0 = blk - 12416; n4 = 256; }
  int i = i0 * 256 + threadIdx.x;
  if (i >= n4) return;
  if (f32mode) {
    float4 v = ((const float4*)src)[i];
    uint2 o;
    o.x = pack_rne(v.x, v.y);
    o.y = pack_rne(v.z, v.w);
    ((uint2*)dst)[i] = o;
  } else {
    ((uint2*)dst)[i] = ((const uint2*)src)[i];
  }
}

// ---------------------------------------------------------------------------
// Shared GEMM mainloop: C[128x128] = A[MxK] * B[NxK]^T, BK=32, 4 waves 2x2.
static __device__ __forceinline__ void gemm_mainloop(
    const u16* __restrict__ A, const u16* __restrict__ Bm, int K,
    int m0, int n0, u16* As, u16* Bs, f32x4 acc[4][4]) {
  const int tid  = threadIdx.x;
  const int lane = tid & 63;
  const int wave = tid >> 6;
  const int n16  = lane & 15;
  const int quad = lane >> 4;
  const int wm = (wave >> 1) * 64;
  const int wn = (wave & 1) * 64;
  const u16* ag = A  + (size_t)(m0 + wave * 16 + (lane >> 2)) * K + (lane & 3) * 8;
  const u16* bg = Bm + (size_t)(n0 + wave * 16 + (lane >> 2)) * K + (lane & 3) * 8;
  u16* al = As + wave * (16 * 32);
  u16* bl = Bs + wave * (16 * 32);
  for (int kt = 0; kt < K; kt += 32) {
    GLD16(ag + kt, al);
    GLD16(ag + (size_t)64 * K + kt, al + 64 * 32);
    GLD16(bg + kt, bl);
    GLD16(bg + (size_t)64 * K + kt, bl + 64 * 32);
    __syncthreads();
    bf16x8 af[4], bf[4];
#pragma unroll
    for (int i = 0; i < 4; i++)
      af[i] = *(const bf16x8*)(As + (wm + i * 16 + n16) * 32 + quad * 8);
#pragma unroll
    for (int j = 0; j < 4; j++)
      bf[j] = *(const bf16x8*)(Bs + (wn + j * 16 + n16) * 32 + quad * 8);
#pragma unroll
    for (int i = 0; i < 4; i++)
#pragma unroll
      for (int j = 0; j < 4; j++)
        acc[i][j] = __builtin_amdgcn_mfma_f32_16x16x32_bf16(af[i], bf[j], acc[i][j], 0, 0, 0);
    __syncthreads();
  }
}

// ---------------------------------------------------------------------------
// K1: qkv = x @ w_qkv^T; q,k -> [B][H][L][D]; v -> [B][H][D][L] (transposed
// in-epilogue: for fixed (i,j), r=0..3 are 4 consecutive l at one d -> b64).
__global__ __launch_bounds__(256) void gemm_qkv(
    const u16* __restrict__ x, const u16* __restrict__ w,
    u16* __restrict__ q_ws, u16* __restrict__ k_ws, u16* __restrict__ vt_ws) {
  __shared__ u16 As[128 * 32];
  __shared__ u16 Bs[128 * 32];
  f32x4 acc[4][4];
#pragma unroll
  for (int i = 0; i < 4; i++)
#pragma unroll
    for (int j = 0; j < 4; j++) acc[i][j] = (f32x4){0.f, 0.f, 0.f, 0.f};
  const int m0 = blockIdx.y * 128;
  const int n0 = blockIdx.x * 128;
  gemm_mainloop(x, w, 1024, m0, n0, As, Bs, acc);
  const int lane = threadIdx.x & 63, wave = threadIdx.x >> 6;
  const int n16 = lane & 15, quad = lane >> 4;
  const int wm = (wave >> 1) * 64, wn = (wave & 1) * 64;
#pragma unroll
  for (int i = 0; i < 4; i++)
#pragma unroll
    for (int j = 0; j < 4; j++) {
      int f = n0 + wn + j * 16 + n16;            // 0..3071
      int which = f >> 10;
      int rem = f & 1023;
      int h = rem >> 6, d = rem & 63;
      int l0 = m0 + wm + i * 16 + quad * 4;      // 4 consecutive rows
      int b = l0 >> 11, l = l0 & 2047;
      if (which == 2) {
        uint2 o;
        o.x = pack_rne(acc[i][j][0], acc[i][j][1]);
        o.y = pack_rne(acc[i][j][2], acc[i][j][3]);
        size_t idx = (((size_t)b * 16 + h) * 64 + d) * 2048 + l;
        *(uint2*)(vt_ws + idx) = o;
      } else {
        u16* dst = (which == 0) ? q_ws : k_ws;
        size_t base = (((size_t)b * 16 + h) * 2048 + l) * 64 + d;
#pragma unroll
        for (int r = 0; r < 4; r++)
          dst[base + (size_t)r * 64] = f32_bf16(acc[i][j][r]);
      }
    }
}

// ---------------------------------------------------------------------------
// K2: RoPE in-place on q and k. q additionally pre-scaled by 0.125*log2(e)
// so flash_attn's softmax is p = exp2(q'.k) with zero extra muls.
#define NP_ROPE 4194304  // B*H*L*(D/2)
__global__ __launch_bounds__(256) void rope_qk(
    u16* __restrict__ q, u16* __restrict__ k,
    const u16* __restrict__ cosp, const u16* __restrict__ sinp) {
  int idx = blockIdx.x * 256 + threadIdx.x;
  bool isq = (idx < NP_ROPE);
  u16* t = isq ? q : k;
  float sc = isq ? 0.18033688011112042f : 1.0f;  // 0.125 * log2(e)
  int p = isq ? idx : idx - NP_ROPE;
  int l = (p >> 5) & 2047;
  int i = p & 31;
  unsigned v = ((unsigned*)t)[p];
  float te = bf16_f32((u16)(v & 0xFFFFu));
  float to = bf16_f32((u16)(v >> 16));
  float c = bf16_f32(cosp[l * 32 + i]);
  float s = bf16_f32(sinp[l * 32 + i]);
  ((unsigned*)t)[p] = pack_rne((te * c - to * s) * sc, (te * s + to * c) * sc);
}

// ---------------------------------------------------------------------------
// K4: flash attention v8. 1-D grid 1024, bh-major (bh=id&63 -> XCD=bh%8;
// same-bh blocks are == mod 64 -> same XCD -> K/V L2 reuse).
// Block = 128 queries, 4 waves x 32 q (2 q-blocks of 16). att[2] pipeline:
// PV(t-1) from registers during iter t; V frags read at end of iter t.
// launch_bounds (256,2): 256-VGPR budget, NO spills (v7 lesson).
__global__ __launch_bounds__(256, 2) void flash_attn(
    const u16* __restrict__ q_ws, const u16* __restrict__ k_ws,
    const u16* __restrict__ vt_ws, u16* __restrict__ o_ws) {
  __shared__ u16 Ks[2][64 * 64];   // [key][d], 16B chunks XOR-swizzled
  __shared__ u16 Vs[2][64 * 64];   // [d][key], 16B chunks XOR-swizzled
  const int bh = blockIdx.x & 63;
  const int q0 = (blockIdx.x >> 6) * 128;
  const int b = bh >> 4, h = bh & 15;
  const int tid = threadIdx.x, lane = tid & 63, wave = tid >> 6;
  const int n16 = lane & 15, quad = lane >> 4;
  const int x7 = n16 & 7;
  // permuted K-row index: swap bits 2<->3 of n16. QK^T output rows then come
  // out key-permuted such that one lane<->lane+32 half-swap of the packed
  // bf16 pairs yields the PV A-fragment (keys quad*8+j) directly.
  const int pn16 = (n16 & 3) | ((n16 & 4) << 1) | ((n16 & 8) >> 1);
  const int px7 = pn16 & 7;
  const size_t hoff = (size_t)bh * (2048 * 64);

  // Q fragments, 2 q-blocks (B-operand: n=q=lane&15, k=d=quad*8+j)
  bf16x8 qf[2][2];
#pragma unroll
  for (int qb = 0; qb < 2; qb++) {
    const u16* qrow = q_ws + hoff + (size_t)(q0 + wave * 32 + qb * 16 + n16) * 64;
    qf[qb][0] = *(const bf16x8*)(qrow + quad * 8);
    qf[qb][1] = *(const bf16x8*)(qrow + 32 + quad * 8);
  }

  f32x4 oacc[2][4];
  f32x4 lq[2];
#pragma unroll
  for (int qb = 0; qb < 2; qb++) {
    lq[qb] = (f32x4){0.f, 0.f, 0.f, 0.f};
#pragma unroll
    for (int s = 0; s < 4; s++) oacc[qb][s] = (f32x4){0.f, 0.f, 0.f, 0.f};
  }

  // staging: lane covers row wave*8+(lane>>3), swizzled chunk (lane&7)^(row&7)
  const int srow = wave * 8 + (lane >> 3);
  const int sw = (lane & 7) ^ ((lane >> 3) & 7);
  const u16* kg = k_ws + hoff + (size_t)srow * 64 + sw * 8;
  const u16* vg = vt_ws + hoff + (size_t)srow * 2048 + sw * 8;
  const int loff = wave * 8 * 64;

  // preload tile 0 into buffer 0
  GLD16(kg, &Ks[0][loff]);
  GLD16(kg + 32 * 64, &Ks[0][loff + 32 * 64]);
  GLD16(vg, &Vs[0][loff]);
  GLD16(vg + (size_t)32 * 2048, &Vs[0][loff + 32 * 64]);

  // att[2] pipeline state: previous tile's P A-frags and V B-frags (regs).
  bf16x8 pfp[2][2];   // [qb][half]
  bf16x8 vfp[4][2];   // [sd][half]

  for (int kt = 0; kt < 2048; kt += 64) {
    const int buf = (kt >> 6) & 1;
    __syncthreads();  // drains tile-kt loads (issued a full compute phase ago)
    if (kt + 64 < 2048) {
      const u16* kgn = kg + (size_t)(kt + 64) * 64;
      const u16* vgn = vg + (kt + 64);
      GLD16(kgn, &Ks[buf ^ 1][loff]);
      GLD16(kgn + 32 * 64, &Ks[buf ^ 1][loff + 32 * 64]);
      GLD16(vgn, &Vs[buf ^ 1][loff]);
      GLD16(vgn + (size_t)32 * 2048, &Vs[buf ^ 1][loff + 32 * 64]);
    }
    const u16* ks = Ks[buf];
    const u16* vs = Vs[buf];

    // S^T per key-16-block (permuted K rows); K frags shared across 2 q-blocks.
    // Lane(n16,quad) after sub s holds actual keys s*16 + {r, r+8, r+4, r+12}
    // for quad = {0,1,2,3}, q = n16; packed to bf16 pairs px (p0,p1), py (p2,p3).
    unsigned pxk[2][4], pyk[2][4];  // [qb][sub]
#pragma unroll
    for (int sub = 0; sub < 4; sub++) {
      const u16* krow = ks + (sub * 16 + pn16) * 64;
      bf16x8 kf0 = *(const bf16x8*)(krow + (quad ^ px7) * 8);
      bf16x8 kf1 = *(const bf16x8*)(krow + ((quad + 4) ^ px7) * 8);
#pragma unroll
      for (int qb = 0; qb < 2; qb++) {
        f32x4 z = (f32x4){0.f, 0.f, 0.f, 0.f};
        __builtin_amdgcn_s_setprio(1);
        z = __builtin_amdgcn_mfma_f32_16x16x32_bf16(kf0, qf[qb][0], z, 0, 0, 0);
        z = __builtin_amdgcn_mfma_f32_16x16x32_bf16(kf1, qf[qb][1], z, 0, 0, 0);
        __builtin_amdgcn_s_setprio(0);
        f32x4 p;
#pragma unroll
        for (int r = 0; r < 4; r++) p[r] = __builtin_amdgcn_exp2f(z[r]);  // q pre-scaled
        lq[qb] += p;
        pxk[qb][sub] = pack_bf16_hw(p[0], p[1]);
        pyk[qb][sub] = pack_bf16_hw(p[2], p[3]);
      }
    }

    // PV(t-1): register-only MFMA cluster, independent of everything above ->
    // overlaps tile t's exp2/pack on the trans/VALU pipes.
    if (kt) {
      __builtin_amdgcn_s_setprio(1);
#pragma unroll
      for (int sd = 0; sd < 4; sd++)
#pragma unroll
        for (int qb = 0; qb < 2; qb++) {
          oacc[qb][sd] = __builtin_amdgcn_mfma_f32_16x16x32_bf16(pfp[qb][0], vfp[sd][0], oacc[qb][sd], 0, 0, 0);
          oacc[qb][sd] = __builtin_amdgcn_mfma_f32_16x16x32_bf16(pfp[qb][1], vfp[sd][1], oacc[qb][sd], 0, 0, 0);
        }
      __builtin_amdgcn_s_setprio(0);
    }

    // In-register transpose: permlane32_swap(a,b) -> r.x=[a_lo|b_lo],
    // r.y=[a_hi|b_hi]. With the pn16 row permutation this yields exactly the
    // PV A-operand: lane(n16,quad) reg m = keys {quad*8+2m, quad*8+2m+1}.
#pragma unroll
    for (int qb = 0; qb < 2; qb++) {
      u32x2 r0 = __builtin_amdgcn_permlane32_swap(pxk[qb][0], pxk[qb][1], false, false);
      u32x2 r1 = __builtin_amdgcn_permlane32_swap(pyk[qb][0], pyk[qb][1], false, false);
      u32x2 r2 = __builtin_amdgcn_permlane32_swap(pxk[qb][2], pxk[qb][3], false, false);
      u32x2 r3 = __builtin_amdgcn_permlane32_swap(pyk[qb][2], pyk[qb][3], false, false);
      pfp[qb][0] = mk_pf(r0.x, r1.x, r0.y, r1.y);
      pfp[qb][1] = mk_pf(r2.x, r3.x, r2.y, r3.y);
    }

    // Read V frags for tile t (consumed next iteration): issued last so the
    // LDS latency hides under barrier + QK(t+1). Safe vs loads(t+2): own
    // lgkm drains at the next barrier before any wave stages into buf(t).
#pragma unroll
    for (int sd = 0; sd < 4; sd++) {
      const u16* vrow = vs + (sd * 16 + n16) * 64;
      vfp[sd][0] = *(const bf16x8*)(vrow + (quad ^ x7) * 8);
      vfp[sd][1] = *(const bf16x8*)(vrow + ((quad + 4) ^ x7) * 8);
    }
  }

  // drain: PV for the final tile.
  __builtin_amdgcn_s_setprio(1);
#pragma unroll
  for (int sd = 0; sd < 4; sd++)
#pragma unroll
    for (int qb = 0; qb < 2; qb++) {
      oacc[qb][sd] = __builtin_amdgcn_mfma_f32_16x16x32_bf16(pfp[qb][0], vfp[sd][0], oacc[qb][sd], 0, 0, 0);
      oacc[qb][sd] = __builtin_amdgcn_mfma_f32_16x16x32_bf16(pfp[qb][1], vfp[sd][1], oacc[qb][sd], 0, 0, 0);
    }
  __builtin_amdgcn_s_setprio(0);

  // epilogue: per q-block, reduce l over quads, normalize, store bf16 o.
#pragma unroll
  for (int qb = 0; qb < 2; qb++) {
    float l = lq[qb][0] + lq[qb][1] + lq[qb][2] + lq[qb][3];
    l += __shfl_xor(l, 16, 64);
    l += __shfl_xor(l, 32, 64);
    float linv = 1.0f / l;
#pragma unroll
    for (int r = 0; r < 4; r++) {
      float lr = __shfl(linv, quad * 4 + r, 64);
      int row = q0 + wave * 32 + qb * 16 + quad * 4 + r;
      size_t base = ((size_t)b * 2048 + row) * 1024 + h * 64;
#pragma unroll
      for (int sd = 0; sd < 4; sd++)
        o_ws[base + sd * 16 + n16] = f32_bf16(oacc[qb][sd][r] * lr);
    }
  }
}

// ---------------------------------------------------------------------------
// K5: out = o @ w_proj^T + b_proj  -- f32 OUTPUT
__global__ __launch_bounds__(256) void gemm_proj(
    const u16* __restrict__ o, const u16* __restrict__ w,
    const u16* __restrict__ bias, float* __restrict__ out) {
  __shared__ u16 As[128 * 32];
  __shared__ u16 Bs[128 * 32];
  f32x4 acc[4][4];
#pragma unroll
  for (int i = 0; i < 4; i++)
#pragma unroll
    for (int j = 0; j < 4; j++) acc[i][j] = (f32x4){0.f, 0.f, 0.f, 0.f};
  const int m0 = blockIdx.y * 128;
  const int n0 = blockIdx.x * 128;
  gemm_mainloop(o, w, 1024, m0, n0, As, Bs, acc);
  const int lane = threadIdx.x & 63, wave = threadIdx.x >> 6;
  const int n16 = lane & 15, quad = lane >> 4;
  const int wm = (wave >> 1) * 64, wn = (wave & 1) * 64;
#pragma unroll
  for (int i = 0; i < 4; i++)
#pragma unroll
    for (int j = 0; j < 4; j++) {
      int f = n0 + wn + j * 16 + n16;
      float bf = bf16_f32(bias[f]);
#pragma unroll
      for (int r = 0; r < 4; r++) {
        int m = m0 + wm + i * 16 + quad * 4 + r;
        out[(size_t)m * 1024 + f] = acc[i][j][r] + bf;
      }
    }
}

// ---------------------------------------------------------------------------
extern "C" void kernel_launch(void* const* d_in, const int* in_sizes, int n_in,
                              void* d_out, int out_size, void* d_ws, size_t ws_size,
                              hipStream_t stream) {
  float* out = (float*)d_out;

  u16* ws = (u16*)d_ws;
  u16* xb     = ws;                   // 8388608  (dead after gemm_qkv)
  u16* wqkvb  = ws + 8388608;         // 3145728
  u16* wprojb = ws + 11534336;        // 1048576
  u16* cosb   = ws + 12582912;        // 65536
  u16* sinb   = ws + 12648448;        // 65536
  u16* biasb  = ws + 12713984;        // 1024
  u16* qb     = ws + 12715008;        // 8388608  [B][H][L][D]
  u16* kb     = ws + 21103616;        // 8388608  [B][H][L][D]
  u16* vtb    = ws + 29492224;        // 8388608  [B][H][D][L]
  u16* ob     = xb;                   // [B][L][C] overlay (xb dead)

  convert_all<<<12417, 256, 0, stream>>>(
      d_in[0], d_in[3], d_in[4], d_in[1], d_in[2], d_in[5],
      xb, wqkvb, wprojb, cosb, sinb, biasb);

  gemm_qkv<<<dim3(24, 64), 256, 0, stream>>>(xb, wqkvb, qb, kb, vtb);
  rope_qk<<<32768, 256, 0, stream>>>(qb, kb, cosb, sinb);
  flash_attn<<<1024, 256, 0, stream>>>(qb, kb, vtb, ob);
  gemm_proj<<<dim3(8, 64), 256, 0, stream>>>(ob, wprojb, biasb, out);
}

// Round 5
// 293.277 us; speedup vs baseline: 1.3176x; 1.0212x over previous
//
#include <hip/hip_runtime.h>
#include <hip/hip_bf16.h>
#include <cstdint>

// ---------------------------------------------------------------------------
// Attention (B=4, L=2048, C=1024, H=16, D=64). f32 in / f32 out, bf16 MFMA.
//   convert_all -> gemm_qkv(+v-transpose AND RoPE fused) -> flash_attn -> gemm_proj
// R5: flash_attn reverted to v6 exactly (93us; R0-R4 proved conflicts,
// occupancy and phase-overlap are all non-limiters; att[2] regressed).
// rope_qk kernel DELETED: RoPE is fused into gemm_qkv's epilogue. Adjacent
// n16 lanes hold the even/odd RoPE pair -> partner via __shfl_xor(v,1);
// cos/sin stored TRANSPOSED [D/2][L] bf16 so 4 consecutive l rows = one
// uint2 load per (i,j). q pre-scale 0.125*log2e folded into the same store.
// Saves the 64MB q/k HBM round-trip + one launch.
// MFMA 16x16x32 bf16 layouts (HW-verified): A/B: [lane&15][(lane>>4)*8+j];
// C/D: col=lane&15, row=(lane>>4)*4+reg.
// permlane32_swap(a,b): r.x = [a_lo | b_lo], r.y = [a_hi | b_hi].
// ---------------------------------------------------------------------------

typedef unsigned short u16;
typedef __attribute__((ext_vector_type(8))) short bf16x8;
typedef __attribute__((ext_vector_type(4))) float f32x4;
typedef __attribute__((ext_vector_type(2))) unsigned int u32x2;

#define GLD16(g, l)                                                            \
  __builtin_amdgcn_global_load_lds(                                            \
      (const __attribute__((address_space(1))) void*)(g),                      \
      (__attribute__((address_space(3))) void*)(l), 16, 0, 0)

static __device__ __forceinline__ u16 f32_bf16(float f) {
  union { float f; unsigned u; } v; v.f = f;
  unsigned r = v.u + 0x7FFFu + ((v.u >> 16) & 1u);  // RNE
  return (u16)(r >> 16);
}
static __device__ __forceinline__ float bf16_f32(u16 h) {
  union { unsigned u; float f; } v; v.u = ((unsigned)h) << 16;
  return v.f;
}
static __device__ __forceinline__ unsigned pack_rne(float a, float b) {
  union { float f; unsigned u; } x, y; x.f = a; y.f = b;
  unsigned ua = x.u + 0x7FFFu + ((x.u >> 16) & 1u);
  unsigned ub = y.u + 0x7FFFu + ((y.u >> 16) & 1u);
  return (ua >> 16) | (ub & 0xFFFF0000u);
}
static __device__ __forceinline__ unsigned pack_bf16_hw(float a, float b) {
  float2 t; t.x = a; t.y = b;
  __hip_bfloat162 h = __float22bfloat162_rn(t);
  union { __hip_bfloat162 h; unsigned u; } c; c.h = h;
  return c.u;
}

// ---------------------------------------------------------------------------
// K0: canonicalize ALL inputs to bf16 in one launch; dtype flag read inline
// (cos[0][0]==1.0f: f32 word 0x3F800000, bf16 pair 0x3F803F80).
// cos/sin are additionally TRANSPOSED to [32][2048] (bf16) for the fused
// RoPE epilogue in gemm_qkv.
__global__ __launch_bounds__(256) void convert_all(
    const void* __restrict__ x, const void* __restrict__ wq,
    const void* __restrict__ wp, const void* __restrict__ cs,
    const void* __restrict__ sn, const void* __restrict__ bs,
    u16* __restrict__ xb, u16* __restrict__ wqb, u16* __restrict__ wpb,
    u16* __restrict__ cb, u16* __restrict__ sb, u16* __restrict__ bb) {
  const unsigned f32mode = (((const unsigned*)cs)[0] == 0x3F800000u);
  int blk = blockIdx.x;
  if (blk >= 12288 && blk < 12416) {
    // cos/sin: read [2048][32], write transposed [32][2048] bf16.
    const void* src = (blk < 12352) ? cs : sn;
    u16* dst = (blk < 12352) ? cb : sb;
    int i = (blk - ((blk < 12352) ? 12288 : 12352)) * 256 + threadIdx.x;  // 0..16383
    u16 e[4];
    if (f32mode) {
      float4 v = ((const float4*)src)[i];
      const float* vf = (const float*)&v;
#pragma unroll
      for (int c = 0; c < 4; c++) e[c] = f32_bf16(vf[c]);
    } else {
      uint2 v = ((const uint2*)src)[i];
      e[0] = (u16)(v.x & 0xFFFFu); e[1] = (u16)(v.x >> 16);
      e[2] = (u16)(v.y & 0xFFFFu); e[3] = (u16)(v.y >> 16);
    }
#pragma unroll
    for (int c = 0; c < 4; c++) {
      int E = i * 4 + c;                  // linear element: l = E>>5, ip = E&31
      dst[(E & 31) * 2048 + (E >> 5)] = e[c];
    }
    return;
  }
  const void* src; u16* dst; int i0, n4;
  if (blk < 8192)       { src = x;  dst = xb;  i0 = blk;         n4 = 2097152; }
  else if (blk < 11264) { src = wq; dst = wqb; i0 = blk - 8192;  n4 = 786432; }
  else if (blk < 12288) { src = wp; dst = wpb; i0 = blk - 11264; n4 = 262144; }
  else                  { src = bs; dst = bb;  i0 = blk - 12416; n4 = 256; }
  int i = i0 * 256 + threadIdx.x;
  if (i >= n4) return;
  if (f32mode) {
    float4 v = ((const float4*)src)[i];
    uint2 o;
    o.x = pack_rne(v.x, v.y);
    o.y = pack_rne(v.z, v.w);
    ((uint2*)dst)[i] = o;
  } else {
    ((uint2*)dst)[i] = ((const uint2*)src)[i];
  }
}

// ---------------------------------------------------------------------------
// Shared GEMM mainloop: C[128x128] = A[MxK] * B[NxK]^T, BK=32, 4 waves 2x2.
static __device__ __forceinline__ void gemm_mainloop(
    const u16* __restrict__ A, const u16* __restrict__ Bm, int K,
    int m0, int n0, u16* As, u16* Bs, f32x4 acc[4][4]) {
  const int tid  = threadIdx.x;
  const int lane = tid & 63;
  const int wave = tid >> 6;
  const int n16  = lane & 15;
  const int quad = lane >> 4;
  const int wm = (wave >> 1) * 64;
  const int wn = (wave & 1) * 64;
  const u16* ag = A  + (size_t)(m0 + wave * 16 + (lane >> 2)) * K + (lane & 3) * 8;
  const u16* bg = Bm + (size_t)(n0 + wave * 16 + (lane >> 2)) * K + (lane & 3) * 8;
  u16* al = As + wave * (16 * 32);
  u16* bl = Bs + wave * (16 * 32);
  for (int kt = 0; kt < K; kt += 32) {
    GLD16(ag + kt, al);
    GLD16(ag + (size_t)64 * K + kt, al + 64 * 32);
    GLD16(bg + kt, bl);
    GLD16(bg + (size_t)64 * K + kt, bl + 64 * 32);
    __syncthreads();
    bf16x8 af[4], bf[4];
#pragma unroll
    for (int i = 0; i < 4; i++)
      af[i] = *(const bf16x8*)(As + (wm + i * 16 + n16) * 32 + quad * 8);
#pragma unroll
    for (int j = 0; j < 4; j++)
      bf[j] = *(const bf16x8*)(Bs + (wn + j * 16 + n16) * 32 + quad * 8);
#pragma unroll
    for (int i = 0; i < 4; i++)
#pragma unroll
      for (int j = 0; j < 4; j++)
        acc[i][j] = __builtin_amdgcn_mfma_f32_16x16x32_bf16(af[i], bf[j], acc[i][j], 0, 0, 0);
    __syncthreads();
  }
}

// ---------------------------------------------------------------------------
// K1: qkv = x @ w_qkv^T; q,k -> [B][H][L][D] WITH RoPE APPLIED (q additionally
// pre-scaled by 0.125*log2e); v -> [B][H][D][L] (transposed in-epilogue).
// RoPE fusion: within a j-block, lane n16 holds d = base+n16, so the even/odd
// pair partner is __shfl_xor(v,1). cos/sin tables are transposed [32][2048]
// bf16 -> one uint2 covers the 4 consecutive l rows (quad*4+r) of this lane.
__global__ __launch_bounds__(256) void gemm_qkv(
    const u16* __restrict__ x, const u16* __restrict__ w,
    u16* __restrict__ q_ws, u16* __restrict__ k_ws, u16* __restrict__ vt_ws,
    const u16* __restrict__ cosT, const u16* __restrict__ sinT) {
  __shared__ u16 As[128 * 32];
  __shared__ u16 Bs[128 * 32];
  f32x4 acc[4][4];
#pragma unroll
  for (int i = 0; i < 4; i++)
#pragma unroll
    for (int j = 0; j < 4; j++) acc[i][j] = (f32x4){0.f, 0.f, 0.f, 0.f};
  const int m0 = blockIdx.y * 128;
  const int n0 = blockIdx.x * 128;
  gemm_mainloop(x, w, 1024, m0, n0, As, Bs, acc);
  const int lane = threadIdx.x & 63, wave = threadIdx.x >> 6;
  const int n16 = lane & 15, quad = lane >> 4;
  const int wm = (wave >> 1) * 64, wn = (wave & 1) * 64;
#pragma unroll
  for (int i = 0; i < 4; i++)
#pragma unroll
    for (int j = 0; j < 4; j++) {
      int f = n0 + wn + j * 16 + n16;            // 0..3071 (wave-uniform which)
      int which = f >> 10;
      int rem = f & 1023;
      int h = rem >> 6, d = rem & 63;
      int l0 = m0 + wm + i * 16 + quad * 4;      // 4 consecutive rows
      int b = l0 >> 11, l = l0 & 2047;
      if (which == 2) {
        uint2 o;
        o.x = pack_rne(acc[i][j][0], acc[i][j][1]);
        o.y = pack_rne(acc[i][j][2], acc[i][j][3]);
        size_t idx = (((size_t)b * 16 + h) * 64 + d) * 2048 + l;
        *(uint2*)(vt_ws + idx) = o;
      } else {
        u16* dst = (which == 0) ? q_ws : k_ws;
        const float sc = (which == 0) ? 0.18033688011112042f : 1.0f;  // 0.125*log2(e)
        const int ip = d >> 1;
        const bool ev = !(d & 1);
        uint2 cu = *(const uint2*)(cosT + ip * 2048 + l);
        uint2 su = *(const uint2*)(sinT + ip * 2048 + l);
        float cf[4] = {bf16_f32((u16)(cu.x & 0xFFFFu)), bf16_f32((u16)(cu.x >> 16)),
                       bf16_f32((u16)(cu.y & 0xFFFFu)), bf16_f32((u16)(cu.y >> 16))};
        float sf[4] = {bf16_f32((u16)(su.x & 0xFFFFu)), bf16_f32((u16)(su.x >> 16)),
                       bf16_f32((u16)(su.y & 0xFFFFu)), bf16_f32((u16)(su.y >> 16))};
        size_t base = (((size_t)b * 16 + h) * 2048 + l) * 64 + d;
#pragma unroll
        for (int r = 0; r < 4; r++) {
          float v = acc[i][j][r];
          float p = __shfl_xor(v, 1, 64);        // partner component (d^1)
          // even d: re = te*c - to*s (v=te, p=to); odd d: ro = te*s + to*c (p=te, v=to)
          float o = ev ? (v * cf[r] - p * sf[r]) : (p * sf[r] + v * cf[r]);
          dst[base + (size_t)r * 64] = f32_bf16(o * sc);
        }
      }
    }
}

// ---------------------------------------------------------------------------
// K4: flash attention v6 (reverted verbatim: the proven 93us version).
// 1-D grid 1024, bh-major (bh=id&63 -> XCD=bh%8; same-bh blocks == mod 64 ->
// same XCD -> K/V L2 reuse). Block = 128 queries, 4 waves x 32 q (2 q-blocks
// of 16). 4 blocks/CU. Double-buffered K/V, single barrier per k-tile,
// prefetch after barrier, P transpose fully in-register via permuted K rows
// (bit2<->bit3 of n16) + permlane32_swap.
__global__ __launch_bounds__(256, 4) void flash_attn(
    const u16* __restrict__ q_ws, const u16* __restrict__ k_ws,
    const u16* __restrict__ vt_ws, u16* __restrict__ o_ws) {
  __shared__ u16 Ks[2][64 * 64];   // [key][d], 16B chunks XOR-swizzled
  __shared__ u16 Vs[2][64 * 64];   // [d][key], 16B chunks XOR-swizzled
  const int bh = blockIdx.x & 63;
  const int q0 = (blockIdx.x >> 6) * 128;
  const int b = bh >> 4, h = bh & 15;
  const int tid = threadIdx.x, lane = tid & 63, wave = tid >> 6;
  const int n16 = lane & 15, quad = lane >> 4;
  const int x7 = n16 & 7;
  const int pn16 = (n16 & 3) | ((n16 & 4) << 1) | ((n16 & 8) >> 1);
  const int px7 = pn16 & 7;
  const size_t hoff = (size_t)bh * (2048 * 64);

  // Q fragments, 2 q-blocks (B-operand: n=q=lane&15, k=d=quad*8+j)
  bf16x8 qf[2][2];
#pragma unroll
  for (int qb = 0; qb < 2; qb++) {
    const u16* qrow = q_ws + hoff + (size_t)(q0 + wave * 32 + qb * 16 + n16) * 64;
    qf[qb][0] = *(const bf16x8*)(qrow + quad * 8);
    qf[qb][1] = *(const bf16x8*)(qrow + 32 + quad * 8);
  }

  f32x4 oacc[2][4];
  f32x4 lq[2];
#pragma unroll
  for (int qb = 0; qb < 2; qb++) {
    lq[qb] = (f32x4){0.f, 0.f, 0.f, 0.f};
#pragma unroll
    for (int s = 0; s < 4; s++) oacc[qb][s] = (f32x4){0.f, 0.f, 0.f, 0.f};
  }

  // staging: lane covers row wave*8+(lane>>3), swizzled chunk (lane&7)^(row&7)
  const int srow = wave * 8 + (lane >> 3);
  const int sw = (lane & 7) ^ ((lane >> 3) & 7);
  const u16* kg = k_ws + hoff + (size_t)srow * 64 + sw * 8;
  const u16* vg = vt_ws + hoff + (size_t)srow * 2048 + sw * 8;
  const int loff = wave * 8 * 64;

  // preload tile 0 into buffer 0
  GLD16(kg, &Ks[0][loff]);
  GLD16(kg + 32 * 64, &Ks[0][loff + 32 * 64]);
  GLD16(vg, &Vs[0][loff]);
  GLD16(vg + (size_t)32 * 2048, &Vs[0][loff + 32 * 64]);

  for (int kt = 0; kt < 2048; kt += 64) {
    const int buf = (kt >> 6) & 1;
    __syncthreads();  // drains tile-kt loads (issued a full compute phase ago)
    if (kt + 64 < 2048) {
      const u16* kgn = kg + (size_t)(kt + 64) * 64;
      const u16* vgn = vg + (kt + 64);
      GLD16(kgn, &Ks[buf ^ 1][loff]);
      GLD16(kgn + 32 * 64, &Ks[buf ^ 1][loff + 32 * 64]);
      GLD16(vgn, &Vs[buf ^ 1][loff]);
      GLD16(vgn + (size_t)32 * 2048, &Vs[buf ^ 1][loff + 32 * 64]);
    }
    const u16* ks = Ks[buf];
    const u16* vs = Vs[buf];

    // S^T per key-16-block (permuted K rows); K frags shared across 2 q-blocks.
    unsigned pxk[2][4], pyk[2][4];  // [qb][sub]
#pragma unroll
    for (int sub = 0; sub < 4; sub++) {
      const u16* krow = ks + (sub * 16 + pn16) * 64;
      bf16x8 kf0 = *(const bf16x8*)(krow + (quad ^ px7) * 8);
      bf16x8 kf1 = *(const bf16x8*)(krow + ((quad + 4) ^ px7) * 8);
#pragma unroll
      for (int qb = 0; qb < 2; qb++) {
        f32x4 z = (f32x4){0.f, 0.f, 0.f, 0.f};
        z = __builtin_amdgcn_mfma_f32_16x16x32_bf16(kf0, qf[qb][0], z, 0, 0, 0);
        z = __builtin_amdgcn_mfma_f32_16x16x32_bf16(kf1, qf[qb][1], z, 0, 0, 0);
        f32x4 p;
#pragma unroll
        for (int r = 0; r < 4; r++) p[r] = __builtin_amdgcn_exp2f(z[r]);  // q pre-scaled
        lq[qb] += p;
        pxk[qb][sub] = pack_bf16_hw(p[0], p[1]);
        pyk[qb][sub] = pack_bf16_hw(p[2], p[3]);
      }
    }

    // In-register transpose -> PV A-operand.
    bf16x8 pf[2][2];
#pragma unroll
    for (int qb = 0; qb < 2; qb++) {
      u32x2 r0 = __builtin_amdgcn_permlane32_swap(pxk[qb][0], pxk[qb][1], false, false);
      u32x2 r1 = __builtin_amdgcn_permlane32_swap(pyk[qb][0], pyk[qb][1], false, false);
      u32x2 r2 = __builtin_amdgcn_permlane32_swap(pxk[qb][2], pxk[qb][3], false, false);
      u32x2 r3 = __builtin_amdgcn_permlane32_swap(pyk[qb][2], pyk[qb][3], false, false);
      union { unsigned u[4]; bf16x8 v; } t0, t1;
      t0.u[0] = r0.x; t0.u[1] = r1.x; t0.u[2] = r0.y; t0.u[3] = r1.y;
      t1.u[0] = r2.x; t1.u[1] = r3.x; t1.u[2] = r2.y; t1.u[3] = r3.y;
      pf[qb][0] = t0.v;
      pf[qb][1] = t1.v;
    }

    // PV: V frags shared across both q-blocks.
#pragma unroll
    for (int sd = 0; sd < 4; sd++) {
      const u16* vrow = vs + (sd * 16 + n16) * 64;
      bf16x8 vf0 = *(const bf16x8*)(vrow + (quad ^ x7) * 8);
      bf16x8 vf1 = *(const bf16x8*)(vrow + ((quad + 4) ^ x7) * 8);
#pragma unroll
      for (int qb = 0; qb < 2; qb++) {
        oacc[qb][sd] = __builtin_amdgcn_mfma_f32_16x16x32_bf16(pf[qb][0], vf0, oacc[qb][sd], 0, 0, 0);
        oacc[qb][sd] = __builtin_amdgcn_mfma_f32_16x16x32_bf16(pf[qb][1], vf1, oacc[qb][sd], 0, 0, 0);
      }
    }
    // no second barrier: next iteration's barrier protects buffer reuse
  }

  // epilogue: per q-block, reduce l over quads, normalize, store bf16 o.
#pragma unroll
  for (int qb = 0; qb < 2; qb++) {
    float l = lq[qb][0] + lq[qb][1] + lq[qb][2] + lq[qb][3];
    l += __shfl_xor(l, 16, 64);
    l += __shfl_xor(l, 32, 64);
    float linv = 1.0f / l;
#pragma unroll
    for (int r = 0; r < 4; r++) {
      float lr = __shfl(linv, quad * 4 + r, 64);
      int row = q0 + wave * 32 + qb * 16 + quad * 4 + r;
      size_t base = ((size_t)b * 2048 + row) * 1024 + h * 64;
#pragma unroll
      for (int sd = 0; sd < 4; sd++)
        o_ws[base + sd * 16 + n16] = f32_bf16(oacc[qb][sd][r] * lr);
    }
  }
}

// ---------------------------------------------------------------------------
// K5: out = o @ w_proj^T + b_proj  -- f32 OUTPUT
__global__ __launch_bounds__(256) void gemm_proj(
    const u16* __restrict__ o, const u16* __restrict__ w,
    const u16* __restrict__ bias, float* __restrict__ out) {
  __shared__ u16 As[128 * 32];
  __shared__ u16 Bs[128 * 32];
  f32x4 acc[4][4];
#pragma unroll
  for (int i = 0; i < 4; i++)
#pragma unroll
    for (int j = 0; j < 4; j++) acc[i][j] = (f32x4){0.f, 0.f, 0.f, 0.f};
  const int m0 = blockIdx.y * 128;
  const int n0 = blockIdx.x * 128;
  gemm_mainloop(o, w, 1024, m0, n0, As, Bs, acc);
  const int lane = threadIdx.x & 63, wave = threadIdx.x >> 6;
  const int n16 = lane & 15, quad = lane >> 4;
  const int wm = (wave >> 1) * 64, wn = (wave & 1) * 64;
#pragma unroll
  for (int i = 0; i < 4; i++)
#pragma unroll
    for (int j = 0; j < 4; j++) {
      int f = n0 + wn + j * 16 + n16;
      float bf = bf16_f32(bias[f]);
#pragma unroll
      for (int r = 0; r < 4; r++) {
        int m = m0 + wm + i * 16 + quad * 4 + r;
        out[(size_t)m * 1024 + f] = acc[i][j][r] + bf;
      }
    }
}

// ---------------------------------------------------------------------------
extern "C" void kernel_launch(void* const* d_in, const int* in_sizes, int n_in,
                              void* d_out, int out_size, void* d_ws, size_t ws_size,
                              hipStream_t stream) {
  float* out = (float*)d_out;

  u16* ws = (u16*)d_ws;
  u16* xb     = ws;                   // 8388608  (dead after gemm_qkv)
  u16* wqkvb  = ws + 8388608;         // 3145728
  u16* wprojb = ws + 11534336;        // 1048576
  u16* cosb   = ws + 12582912;        // 65536  [32][2048] transposed bf16
  u16* sinb   = ws + 12648448;        // 65536  [32][2048] transposed bf16
  u16* biasb  = ws + 12713984;        // 1024
  u16* qb     = ws + 12715008;        // 8388608  [B][H][L][D]
  u16* kb     = ws + 21103616;        // 8388608  [B][H][L][D]
  u16* vtb    = ws + 29492224;        // 8388608  [B][H][D][L]
  u16* ob     = xb;                   // [B][L][C] overlay (xb dead)

  convert_all<<<12417, 256, 0, stream>>>(
      d_in[0], d_in[3], d_in[4], d_in[1], d_in[2], d_in[5],
      xb, wqkvb, wprojb, cosb, sinb, biasb);

  gemm_qkv<<<dim3(24, 64), 256, 0, stream>>>(xb, wqkvb, qb, kb, vtb, cosb, sinb);
  flash_attn<<<1024, 256, 0, stream>>>(qb, kb, vtb, ob);
  gemm_proj<<<dim3(8, 64), 256, 0, stream>>>(ob, wprojb, biasb, out);
}

// Round 6
// 279.238 us; speedup vs baseline: 1.3838x; 1.0503x over previous
//
#include <hip/hip_runtime.h>
#include <hip/hip_bf16.h>
#include <cstdint>

// ---------------------------------------------------------------------------
// Attention (B=4, L=2048, C=1024, H=16, D=64). f32 in / f32 out, bf16 MFMA.
//   convert_all -> gemm_qkv(+v-transpose AND RoPE fused) -> flash_attn -> gemm_proj
// R6: gemm_mainloop gets the SAME double-buffer/prefetch-after-barrier
// schedule flash_attn already uses. The old loop staged tile t then
// immediately barriered (vmcnt(0) drain) -> every one of the 32 K-iters
// serially ate full load latency with ~1.6 blocks/CU of TLP to hide it
// (R5 counters: MfmaUtil 22, VALUBusy 17, Occ 19.7 -> both pipes idle,
// stall-bound). Now loads for t+1 are issued right after the barrier and
// drained by the NEXT iteration's barrier, a full compute phase later.
// One barrier per K-tile. LDS 16->32KB (still 5 blocks/CU at VGPR 88).
// flash_attn v6 untouched (93us; R0-R4 proved conflicts/occupancy/phase-
// overlap are all non-limiters there).
// MFMA 16x16x32 bf16 layouts (HW-verified): A/B: [lane&15][(lane>>4)*8+j];
// C/D: col=lane&15, row=(lane>>4)*4+reg.
// permlane32_swap(a,b): r.x = [a_lo | b_lo], r.y = [a_hi | b_hi].
// ---------------------------------------------------------------------------

typedef unsigned short u16;
typedef __attribute__((ext_vector_type(8))) short bf16x8;
typedef __attribute__((ext_vector_type(4))) float f32x4;
typedef __attribute__((ext_vector_type(2))) unsigned int u32x2;

#define GLD16(g, l)                                                            \
  __builtin_amdgcn_global_load_lds(                                            \
      (const __attribute__((address_space(1))) void*)(g),                      \
      (__attribute__((address_space(3))) void*)(l), 16, 0, 0)

static __device__ __forceinline__ u16 f32_bf16(float f) {
  union { float f; unsigned u; } v; v.f = f;
  unsigned r = v.u + 0x7FFFu + ((v.u >> 16) & 1u);  // RNE
  return (u16)(r >> 16);
}
static __device__ __forceinline__ float bf16_f32(u16 h) {
  union { unsigned u; float f; } v; v.u = ((unsigned)h) << 16;
  return v.f;
}
static __device__ __forceinline__ unsigned pack_rne(float a, float b) {
  union { float f; unsigned u; } x, y; x.f = a; y.f = b;
  unsigned ua = x.u + 0x7FFFu + ((x.u >> 16) & 1u);
  unsigned ub = y.u + 0x7FFFu + ((y.u >> 16) & 1u);
  return (ua >> 16) | (ub & 0xFFFF0000u);
}
static __device__ __forceinline__ unsigned pack_bf16_hw(float a, float b) {
  float2 t; t.x = a; t.y = b;
  __hip_bfloat162 h = __float22bfloat162_rn(t);
  union { __hip_bfloat162 h; unsigned u; } c; c.h = h;
  return c.u;
}

// ---------------------------------------------------------------------------
// K0: canonicalize ALL inputs to bf16 in one launch; dtype flag read inline
// (cos[0][0]==1.0f: f32 word 0x3F800000, bf16 pair 0x3F803F80).
// cos/sin are additionally TRANSPOSED to [32][2048] (bf16) for the fused
// RoPE epilogue in gemm_qkv.
__global__ __launch_bounds__(256) void convert_all(
    const void* __restrict__ x, const void* __restrict__ wq,
    const void* __restrict__ wp, const void* __restrict__ cs,
    const void* __restrict__ sn, const void* __restrict__ bs,
    u16* __restrict__ xb, u16* __restrict__ wqb, u16* __restrict__ wpb,
    u16* __restrict__ cb, u16* __restrict__ sb, u16* __restrict__ bb) {
  const unsigned f32mode = (((const unsigned*)cs)[0] == 0x3F800000u);
  int blk = blockIdx.x;
  if (blk >= 12288 && blk < 12416) {
    // cos/sin: read [2048][32], write transposed [32][2048] bf16.
    const void* src = (blk < 12352) ? cs : sn;
    u16* dst = (blk < 12352) ? cb : sb;
    int i = (blk - ((blk < 12352) ? 12288 : 12352)) * 256 + threadIdx.x;  // 0..16383
    u16 e[4];
    if (f32mode) {
      float4 v = ((const float4*)src)[i];
      const float* vf = (const float*)&v;
#pragma unroll
      for (int c = 0; c < 4; c++) e[c] = f32_bf16(vf[c]);
    } else {
      uint2 v = ((const uint2*)src)[i];
      e[0] = (u16)(v.x & 0xFFFFu); e[1] = (u16)(v.x >> 16);
      e[2] = (u16)(v.y & 0xFFFFu); e[3] = (u16)(v.y >> 16);
    }
#pragma unroll
    for (int c = 0; c < 4; c++) {
      int E = i * 4 + c;                  // linear element: l = E>>5, ip = E&31
      dst[(E & 31) * 2048 + (E >> 5)] = e[c];
    }
    return;
  }
  const void* src; u16* dst; int i0, n4;
  if (blk < 8192)       { src = x;  dst = xb;  i0 = blk;         n4 = 2097152; }
  else if (blk < 11264) { src = wq; dst = wqb; i0 = blk - 8192;  n4 = 786432; }
  else if (blk < 12288) { src = wp; dst = wpb; i0 = blk - 11264; n4 = 262144; }
  else                  { src = bs; dst = bb;  i0 = blk - 12416; n4 = 256; }
  int i = i0 * 256 + threadIdx.x;
  if (i >= n4) return;
  if (f32mode) {
    float4 v = ((const float4*)src)[i];
    uint2 o;
    o.x = pack_rne(v.x, v.y);
    o.y = pack_rne(v.z, v.w);
    ((uint2*)dst)[i] = o;
  } else {
    ((uint2*)dst)[i] = ((const uint2*)src)[i];
  }
}

// ---------------------------------------------------------------------------
// Shared GEMM mainloop: C[128x128] = A[MxK] * B[NxK]^T, BK=32, 4 waves 2x2.
// Double-buffered (flash-style): preload tile 0; each iter barriers (drains
// loads issued a full compute phase ago), prefetches t+1, then ds_read+MFMA
// on tile t. ONE barrier per tile. As/Bs are [2][128*32] u16.
static __device__ __forceinline__ void gemm_mainloop(
    const u16* __restrict__ A, const u16* __restrict__ Bm, int K,
    int m0, int n0, u16* As, u16* Bs, f32x4 acc[4][4]) {
  const int tid  = threadIdx.x;
  const int lane = tid & 63;
  const int wave = tid >> 6;
  const int n16  = lane & 15;
  const int quad = lane >> 4;
  const int wm = (wave >> 1) * 64;
  const int wn = (wave & 1) * 64;
  const u16* ag = A  + (size_t)(m0 + wave * 16 + (lane >> 2)) * K + (lane & 3) * 8;
  const u16* bg = Bm + (size_t)(n0 + wave * 16 + (lane >> 2)) * K + (lane & 3) * 8;
  u16* al = As + wave * (16 * 32);
  u16* bl = Bs + wave * (16 * 32);
  // preload tile 0 into buffer 0
  GLD16(ag, al);
  GLD16(ag + (size_t)64 * K, al + 64 * 32);
  GLD16(bg, bl);
  GLD16(bg + (size_t)64 * K, bl + 64 * 32);
  for (int kt = 0; kt < K; kt += 32) {
    const int buf = (kt >> 5) & 1;
    __syncthreads();  // drains tile-kt loads (issued a full compute phase ago)
    if (kt + 32 < K) {
      const int nb = buf ^ 1;
      GLD16(ag + kt + 32, al + nb * 4096);
      GLD16(ag + (size_t)64 * K + kt + 32, al + nb * 4096 + 64 * 32);
      GLD16(bg + kt + 32, bl + nb * 4096);
      GLD16(bg + (size_t)64 * K + kt + 32, bl + nb * 4096 + 64 * 32);
    }
    const u16* as = As + buf * 4096;
    const u16* bs = Bs + buf * 4096;
    bf16x8 af[4], bf[4];
#pragma unroll
    for (int i = 0; i < 4; i++)
      af[i] = *(const bf16x8*)(as + (wm + i * 16 + n16) * 32 + quad * 8);
#pragma unroll
    for (int j = 0; j < 4; j++)
      bf[j] = *(const bf16x8*)(bs + (wn + j * 16 + n16) * 32 + quad * 8);
#pragma unroll
    for (int i = 0; i < 4; i++)
#pragma unroll
      for (int j = 0; j < 4; j++)
        acc[i][j] = __builtin_amdgcn_mfma_f32_16x16x32_bf16(af[i], bf[j], acc[i][j], 0, 0, 0);
    // no second barrier: next iteration's barrier protects buffer reuse
  }
}

// ---------------------------------------------------------------------------
// K1: qkv = x @ w_qkv^T; q,k -> [B][H][L][D] WITH RoPE APPLIED (q additionally
// pre-scaled by 0.125*log2e); v -> [B][H][D][L] (transposed in-epilogue).
// RoPE fusion: within a j-block, lane n16 holds d = base+n16, so the even/odd
// pair partner is __shfl_xor(v,1). cos/sin tables are transposed [32][2048]
// bf16 -> one uint2 covers the 4 consecutive l rows (quad*4+r) of this lane.
__global__ __launch_bounds__(256) void gemm_qkv(
    const u16* __restrict__ x, const u16* __restrict__ w,
    u16* __restrict__ q_ws, u16* __restrict__ k_ws, u16* __restrict__ vt_ws,
    const u16* __restrict__ cosT, const u16* __restrict__ sinT) {
  __shared__ u16 As[2 * 128 * 32];
  __shared__ u16 Bs[2 * 128 * 32];
  f32x4 acc[4][4];
#pragma unroll
  for (int i = 0; i < 4; i++)
#pragma unroll
    for (int j = 0; j < 4; j++) acc[i][j] = (f32x4){0.f, 0.f, 0.f, 0.f};
  const int m0 = blockIdx.y * 128;
  const int n0 = blockIdx.x * 128;
  gemm_mainloop(x, w, 1024, m0, n0, As, Bs, acc);
  const int lane = threadIdx.x & 63, wave = threadIdx.x >> 6;
  const int n16 = lane & 15, quad = lane >> 4;
  const int wm = (wave >> 1) * 64, wn = (wave & 1) * 64;
#pragma unroll
  for (int i = 0; i < 4; i++)
#pragma unroll
    for (int j = 0; j < 4; j++) {
      int f = n0 + wn + j * 16 + n16;            // 0..3071 (wave-uniform which)
      int which = f >> 10;
      int rem = f & 1023;
      int h = rem >> 6, d = rem & 63;
      int l0 = m0 + wm + i * 16 + quad * 4;      // 4 consecutive rows
      int b = l0 >> 11, l = l0 & 2047;
      if (which == 2) {
        uint2 o;
        o.x = pack_rne(acc[i][j][0], acc[i][j][1]);
        o.y = pack_rne(acc[i][j][2], acc[i][j][3]);
        size_t idx = (((size_t)b * 16 + h) * 64 + d) * 2048 + l;
        *(uint2*)(vt_ws + idx) = o;
      } else {
        u16* dst = (which == 0) ? q_ws : k_ws;
        const float sc = (which == 0) ? 0.18033688011112042f : 1.0f;  // 0.125*log2(e)
        const int ip = d >> 1;
        const bool ev = !(d & 1);
        uint2 cu = *(const uint2*)(cosT + ip * 2048 + l);
        uint2 su = *(const uint2*)(sinT + ip * 2048 + l);
        float cf[4] = {bf16_f32((u16)(cu.x & 0xFFFFu)), bf16_f32((u16)(cu.x >> 16)),
                       bf16_f32((u16)(cu.y & 0xFFFFu)), bf16_f32((u16)(cu.y >> 16))};
        float sf[4] = {bf16_f32((u16)(su.x & 0xFFFFu)), bf16_f32((u16)(su.x >> 16)),
                       bf16_f32((u16)(su.y & 0xFFFFu)), bf16_f32((u16)(su.y >> 16))};
        size_t base = (((size_t)b * 16 + h) * 2048 + l) * 64 + d;
#pragma unroll
        for (int r = 0; r < 4; r++) {
          float v = acc[i][j][r];
          float p = __shfl_xor(v, 1, 64);        // partner component (d^1)
          // even d: re = te*c - to*s (v=te, p=to); odd d: ro = te*s + to*c (p=te, v=to)
          float o = ev ? (v * cf[r] - p * sf[r]) : (p * sf[r] + v * cf[r]);
          dst[base + (size_t)r * 64] = f32_bf16(o * sc);
        }
      }
    }
}

// ---------------------------------------------------------------------------
// K4: flash attention v6 (the proven 93us version, untouched).
// 1-D grid 1024, bh-major (bh=id&63 -> XCD=bh%8; same-bh blocks == mod 64 ->
// same XCD -> K/V L2 reuse). Block = 128 queries, 4 waves x 32 q (2 q-blocks
// of 16). 4 blocks/CU. Double-buffered K/V, single barrier per k-tile,
// prefetch after barrier, P transpose fully in-register via permuted K rows
// (bit2<->bit3 of n16) + permlane32_swap.
__global__ __launch_bounds__(256, 4) void flash_attn(
    const u16* __restrict__ q_ws, const u16* __restrict__ k_ws,
    const u16* __restrict__ vt_ws, u16* __restrict__ o_ws) {
  __shared__ u16 Ks[2][64 * 64];   // [key][d], 16B chunks XOR-swizzled
  __shared__ u16 Vs[2][64 * 64];   // [d][key], 16B chunks XOR-swizzled
  const int bh = blockIdx.x & 63;
  const int q0 = (blockIdx.x >> 6) * 128;
  const int b = bh >> 4, h = bh & 15;
  const int tid = threadIdx.x, lane = tid & 63, wave = tid >> 6;
  const int n16 = lane & 15, quad = lane >> 4;
  const int x7 = n16 & 7;
  const int pn16 = (n16 & 3) | ((n16 & 4) << 1) | ((n16 & 8) >> 1);
  const int px7 = pn16 & 7;
  const size_t hoff = (size_t)bh * (2048 * 64);

  // Q fragments, 2 q-blocks (B-operand: n=q=lane&15, k=d=quad*8+j)
  bf16x8 qf[2][2];
#pragma unroll
  for (int qb = 0; qb < 2; qb++) {
    const u16* qrow = q_ws + hoff + (size_t)(q0 + wave * 32 + qb * 16 + n16) * 64;
    qf[qb][0] = *(const bf16x8*)(qrow + quad * 8);
    qf[qb][1] = *(const bf16x8*)(qrow + 32 + quad * 8);
  }

  f32x4 oacc[2][4];
  f32x4 lq[2];
#pragma unroll
  for (int qb = 0; qb < 2; qb++) {
    lq[qb] = (f32x4){0.f, 0.f, 0.f, 0.f};
#pragma unroll
    for (int s = 0; s < 4; s++) oacc[qb][s] = (f32x4){0.f, 0.f, 0.f, 0.f};
  }

  // staging: lane covers row wave*8+(lane>>3), swizzled chunk (lane&7)^(row&7)
  const int srow = wave * 8 + (lane >> 3);
  const int sw = (lane & 7) ^ ((lane >> 3) & 7);
  const u16* kg = k_ws + hoff + (size_t)srow * 64 + sw * 8;
  const u16* vg = vt_ws + hoff + (size_t)srow * 2048 + sw * 8;
  const int loff = wave * 8 * 64;

  // preload tile 0 into buffer 0
  GLD16(kg, &Ks[0][loff]);
  GLD16(kg + 32 * 64, &Ks[0][loff + 32 * 64]);
  GLD16(vg, &Vs[0][loff]);
  GLD16(vg + (size_t)32 * 2048, &Vs[0][loff + 32 * 64]);

  for (int kt = 0; kt < 2048; kt += 64) {
    const int buf = (kt >> 6) & 1;
    __syncthreads();  // drains tile-kt loads (issued a full compute phase ago)
    if (kt + 64 < 2048) {
      const u16* kgn = kg + (size_t)(kt + 64) * 64;
      const u16* vgn = vg + (kt + 64);
      GLD16(kgn, &Ks[buf ^ 1][loff]);
      GLD16(kgn + 32 * 64, &Ks[buf ^ 1][loff + 32 * 64]);
      GLD16(vgn, &Vs[buf ^ 1][loff]);
      GLD16(vgn + (size_t)32 * 2048, &Vs[buf ^ 1][loff + 32 * 64]);
    }
    const u16* ks = Ks[buf];
    const u16* vs = Vs[buf];

    // S^T per key-16-block (permuted K rows); K frags shared across 2 q-blocks.
    unsigned pxk[2][4], pyk[2][4];  // [qb][sub]
#pragma unroll
    for (int sub = 0; sub < 4; sub++) {
      const u16* krow = ks + (sub * 16 + pn16) * 64;
      bf16x8 kf0 = *(const bf16x8*)(krow + (quad ^ px7) * 8);
      bf16x8 kf1 = *(const bf16x8*)(krow + ((quad + 4) ^ px7) * 8);
#pragma unroll
      for (int qb = 0; qb < 2; qb++) {
        f32x4 z = (f32x4){0.f, 0.f, 0.f, 0.f};
        z = __builtin_amdgcn_mfma_f32_16x16x32_bf16(kf0, qf[qb][0], z, 0, 0, 0);
        z = __builtin_amdgcn_mfma_f32_16x16x32_bf16(kf1, qf[qb][1], z, 0, 0, 0);
        f32x4 p;
#pragma unroll
        for (int r = 0; r < 4; r++) p[r] = __builtin_amdgcn_exp2f(z[r]);  // q pre-scaled
        lq[qb] += p;
        pxk[qb][sub] = pack_bf16_hw(p[0], p[1]);
        pyk[qb][sub] = pack_bf16_hw(p[2], p[3]);
      }
    }

    // In-register transpose -> PV A-operand.
    bf16x8 pf[2][2];
#pragma unroll
    for (int qb = 0; qb < 2; qb++) {
      u32x2 r0 = __builtin_amdgcn_permlane32_swap(pxk[qb][0], pxk[qb][1], false, false);
      u32x2 r1 = __builtin_amdgcn_permlane32_swap(pyk[qb][0], pyk[qb][1], false, false);
      u32x2 r2 = __builtin_amdgcn_permlane32_swap(pxk[qb][2], pxk[qb][3], false, false);
      u32x2 r3 = __builtin_amdgcn_permlane32_swap(pyk[qb][2], pyk[qb][3], false, false);
      union { unsigned u[4]; bf16x8 v; } t0, t1;
      t0.u[0] = r0.x; t0.u[1] = r1.x; t0.u[2] = r0.y; t0.u[3] = r1.y;
      t1.u[0] = r2.x; t1.u[1] = r3.x; t1.u[2] = r2.y; t1.u[3] = r3.y;
      pf[qb][0] = t0.v;
      pf[qb][1] = t1.v;
    }

    // PV: V frags shared across both q-blocks.
#pragma unroll
    for (int sd = 0; sd < 4; sd++) {
      const u16* vrow = vs + (sd * 16 + n16) * 64;
      bf16x8 vf0 = *(const bf16x8*)(vrow + (quad ^ x7) * 8);
      bf16x8 vf1 = *(const bf16x8*)(vrow + ((quad + 4) ^ x7) * 8);
#pragma unroll
      for (int qb = 0; qb < 2; qb++) {
        oacc[qb][sd] = __builtin_amdgcn_mfma_f32_16x16x32_bf16(pf[qb][0], vf0, oacc[qb][sd], 0, 0, 0);
        oacc[qb][sd] = __builtin_amdgcn_mfma_f32_16x16x32_bf16(pf[qb][1], vf1, oacc[qb][sd], 0, 0, 0);
      }
    }
    // no second barrier: next iteration's barrier protects buffer reuse
  }

  // epilogue: per q-block, reduce l over quads, normalize, store bf16 o.
#pragma unroll
  for (int qb = 0; qb < 2; qb++) {
    float l = lq[qb][0] + lq[qb][1] + lq[qb][2] + lq[qb][3];
    l += __shfl_xor(l, 16, 64);
    l += __shfl_xor(l, 32, 64);
    float linv = 1.0f / l;
#pragma unroll
    for (int r = 0; r < 4; r++) {
      float lr = __shfl(linv, quad * 4 + r, 64);
      int row = q0 + wave * 32 + qb * 16 + quad * 4 + r;
      size_t base = ((size_t)b * 2048 + row) * 1024 + h * 64;
#pragma unroll
      for (int sd = 0; sd < 4; sd++)
        o_ws[base + sd * 16 + n16] = f32_bf16(oacc[qb][sd][r] * lr);
    }
  }
}

// ---------------------------------------------------------------------------
// K5: out = o @ w_proj^T + b_proj  -- f32 OUTPUT
__global__ __launch_bounds__(256) void gemm_proj(
    const u16* __restrict__ o, const u16* __restrict__ w,
    const u16* __restrict__ bias, float* __restrict__ out) {
  __shared__ u16 As[2 * 128 * 32];
  __shared__ u16 Bs[2 * 128 * 32];
  f32x4 acc[4][4];
#pragma unroll
  for (int i = 0; i < 4; i++)
#pragma unroll
    for (int j = 0; j < 4; j++) acc[i][j] = (f32x4){0.f, 0.f, 0.f, 0.f};
  const int m0 = blockIdx.y * 128;
  const int n0 = blockIdx.x * 128;
  gemm_mainloop(o, w, 1024, m0, n0, As, Bs, acc);
  const int lane = threadIdx.x & 63, wave = threadIdx.x >> 6;
  const int n16 = lane & 15, quad = lane >> 4;
  const int wm = (wave >> 1) * 64, wn = (wave & 1) * 64;
#pragma unroll
  for (int i = 0; i < 4; i++)
#pragma unroll
    for (int j = 0; j < 4; j++) {
      int f = n0 + wn + j * 16 + n16;
      float bf = bf16_f32(bias[f]);
#pragma unroll
      for (int r = 0; r < 4; r++) {
        int m = m0 + wm + i * 16 + quad * 4 + r;
        out[(size_t)m * 1024 + f] = acc[i][j][r] + bf;
      }
    }
}

// ---------------------------------------------------------------------------
extern "C" void kernel_launch(void* const* d_in, const int* in_sizes, int n_in,
                              void* d_out, int out_size, void* d_ws, size_t ws_size,
                              hipStream_t stream) {
  float* out = (float*)d_out;

  u16* ws = (u16*)d_ws;
  u16* xb     = ws;                   // 8388608  (dead after gemm_qkv)
  u16* wqkvb  = ws + 8388608;         // 3145728
  u16* wprojb = ws + 11534336;        // 1048576
  u16* cosb   = ws + 12582912;        // 65536  [32][2048] transposed bf16
  u16* sinb   = ws + 12648448;        // 65536  [32][2048] transposed bf16
  u16* biasb  = ws + 12713984;        // 1024
  u16* qb     = ws + 12715008;        // 8388608  [B][H][L][D]
  u16* kb     = ws + 21103616;        // 8388608  [B][H][L][D]
  u16* vtb    = ws + 29492224;        // 8388608  [B][H][D][L]
  u16* ob     = xb;                   // [B][L][C] overlay (xb dead)

  convert_all<<<12417, 256, 0, stream>>>(
      d_in[0], d_in[3], d_in[4], d_in[1], d_in[2], d_in[5],
      xb, wqkvb, wprojb, cosb, sinb, biasb);

  gemm_qkv<<<dim3(24, 64), 256, 0, stream>>>(xb, wqkvb, qb, kb, vtb, cosb, sinb);
  flash_attn<<<1024, 256, 0, stream>>>(qb, kb, vtb, ob);
  gemm_proj<<<dim3(8, 64), 256, 0, stream>>>(ob, wprojb, biasb, out);
}